// Round 9
// baseline (1301.901 us; speedup 1.0000x reference)
//
#include <hip/hip_runtime.h>
#include <hip/hip_bf16.h>

#define N_TOK 16384
#define DIM   1024
#define NEXP  4
#define HID   4096

typedef __attribute__((ext_vector_type(8))) short short8;
typedef __attribute__((ext_vector_type(4))) short short4v;
typedef __attribute__((ext_vector_type(4))) float float4v;

static __device__ __forceinline__ short f2bf(float f) {
  __hip_bfloat16 h = __float2bfloat16(f);
  return *reinterpret_cast<short*>(&h);
}

#define GLOAD_LDS16(gsrc, ldst)                                                            \
  __builtin_amdgcn_global_load_lds((const __attribute__((address_space(1))) void*)(gsrc),  \
                                   (__attribute__((address_space(3))) void*)(ldst), 16, 0, 0)

// -------- fused gate (softmax(concat(q,k)@Wg+bg)) + q->bf16 convert --------
__global__ void gatecvt_kernel(const float* __restrict__ q, const float* __restrict__ k,
                               const float* __restrict__ Wg, const float* __restrict__ bg,
                               float* __restrict__ gate, short* __restrict__ qb) {
  const int wave = threadIdx.x >> 6, lane = threadIdx.x & 63;
  const int n = blockIdx.x * 4 + wave;
  const float* qr = q + (size_t)n * DIM;
  const float* kr = k + (size_t)n * DIM;
  short* qbr = qb + (size_t)n * DIM;
  float s0 = 0.f, s1 = 0.f, s2 = 0.f, s3 = 0.f;
#pragma unroll
  for (int it = 0; it < 4; ++it) {
    int d = it * 256 + lane * 4;
    float4 qv = *(const float4*)(qr + d);
    float4 kv = *(const float4*)(kr + d);
    short4v o;
    o[0] = f2bf(qv.x); o[1] = f2bf(qv.y); o[2] = f2bf(qv.z); o[3] = f2bf(qv.w);
    *(short4v*)(qbr + d) = o;
    const float xq[4] = {qv.x, qv.y, qv.z, qv.w};
    const float xk[4] = {kv.x, kv.y, kv.z, kv.w};
#pragma unroll
    for (int j = 0; j < 4; ++j) {
      float4 w = *(const float4*)(Wg + (size_t)(d + j) * 4);
      s0 += xq[j] * w.x; s1 += xq[j] * w.y; s2 += xq[j] * w.z; s3 += xq[j] * w.w;
      float4 w2 = *(const float4*)(Wg + (size_t)(DIM + d + j) * 4);
      s0 += xk[j] * w2.x; s1 += xk[j] * w2.y; s2 += xk[j] * w2.z; s3 += xk[j] * w2.w;
    }
  }
  for (int off = 32; off; off >>= 1) {
    s0 += __shfl_xor(s0, off);
    s1 += __shfl_xor(s1, off);
    s2 += __shfl_xor(s2, off);
    s3 += __shfl_xor(s3, off);
  }
  if (lane == 0) {
    float l0 = s0 + bg[0], l1 = s1 + bg[1], l2 = s2 + bg[2], l3 = s3 + bg[3];
    float m = fmaxf(fmaxf(l0, l1), fmaxf(l2, l3));
    float e0 = expf(l0 - m), e1 = expf(l1 - m), e2 = expf(l2 - m), e3 = expf(l3 - m);
    float inv = 1.f / (e0 + e1 + e2 + e3);
    float4 g; g.x = e0 * inv; g.y = e1 * inv; g.z = e2 * inv; g.w = e3 * inv;
    *(float4*)(gate + (size_t)n * 4) = g;
  }
}

// ---- LDS-tiled transpose+convert: in[z][R][C] f32 -> out[z][C][R] bf16 ----
__global__ void transpose_bf16_kernel(const float* __restrict__ in, short* __restrict__ out,
                                      int R, int C) {
  __shared__ float tile[64][65];
  const size_t eoff = (size_t)blockIdx.z * (size_t)R * C;
  const float* src = in + eoff;
  short* dst = out + eoff;
  const int r0 = blockIdx.y * 64, c0 = blockIdx.x * 64;
  const int tc = threadIdx.x & 63, tr = threadIdx.x >> 6;
#pragma unroll
  for (int p = 0; p < 16; ++p) {
    int r = p * 4 + tr;
    tile[r][tc] = src[(size_t)(r0 + r) * C + (c0 + tc)];
  }
  __syncthreads();
#pragma unroll
  for (int p = 0; p < 16; ++p) {
    int i = p * 4 + tr;
    dst[(size_t)(c0 + i) * R + (r0 + tc)] = f2bf(tile[tc][i]);
  }
}

// ===== R7-proven 128x128 GEMM body (880 TF class) =====
template <int MODE>
__device__ __forceinline__ void gemm_body(short* sA, short* sB,
                                          const short* __restrict__ A, const short* __restrict__ Bt,
                                          int K, int NTM, int NTN, int bid,
                                          const float* __restrict__ bias,
                                          const float* __restrict__ gate4,
                                          short* __restrict__ OutB, float* __restrict__ FOut,
                                          int ldc, int accumulate) {
  int tile_m, tile_n;
  {
    const int m_own = NTM >> 3;
    const int xcd = bid & 7;
    const int idx = bid >> 3;
    const int mgrp = (m_own < 8) ? m_own : 8;
    const int per = mgrp * 4;
    const int pos = idx % per;
    const int chunk = idx / per;
    const int ml = pos % mgrp;
    const int nl = pos / mgrp;
    const int nchunks = NTN >> 2;
    const int nc = chunk % nchunks;
    const int mg2 = chunk / nchunks;
    tile_m = xcd * m_own + mg2 * mgrp + ml;
    tile_n = nc * 4 + nl;
  }
  const int m0 = tile_m * 128;
  const int n0 = tile_n * 128;

  const int t = threadIdx.x;
  const int lane = t & 63;
  const int wave = t >> 6;
  const int wm = (wave >> 1) * 64;
  const int wn = (wave & 1) * 64;
  const int r16 = lane & 15;
  const int kg = lane >> 4;

  float4v acc[4][4];
#pragma unroll
  for (int m = 0; m < 4; ++m)
#pragma unroll
    for (int n = 0; n < 4; ++n) acc[m][n] = (float4v)0.0f;

  for (int k0 = 0; k0 < K; k0 += 64) {
#pragma unroll
    for (int i = 0; i < 4; ++i) {
      int c = i * 256 + t;
      int row = c >> 3;
      int jc = (c & 7) ^ (row & 7);
      GLOAD_LDS16(A + (size_t)(m0 + row) * K + k0 + jc * 8, &sA[c * 8]);
      GLOAD_LDS16(Bt + (size_t)(n0 + row) * K + k0 + jc * 8, &sB[c * 8]);
    }
    __syncthreads();
#pragma unroll
    for (int kk = 0; kk < 2; ++kk) {
      short8 af[4], bfr[4];
#pragma unroll
      for (int m = 0; m < 4; ++m) {
        int row = wm + m * 16 + r16;
        int jc = (kk * 4 + kg) ^ (row & 7);
        af[m] = *(const short8*)&sA[row * 64 + jc * 8];
      }
#pragma unroll
      for (int n = 0; n < 4; ++n) {
        int row = wn + n * 16 + r16;
        int jc = (kk * 4 + kg) ^ (row & 7);
        bfr[n] = *(const short8*)&sB[row * 64 + jc * 8];
      }
#pragma unroll
      for (int m = 0; m < 4; ++m)
#pragma unroll
        for (int n = 0; n < 4; ++n)
          acc[m][n] = __builtin_amdgcn_mfma_f32_16x16x32_bf16(af[m], bfr[n], acc[m][n], 0, 0, 0);
    }
    __syncthreads();
  }

#pragma unroll
  for (int m = 0; m < 4; ++m) {
    int rbase = m0 + wm + m * 16 + kg * 4;
#pragma unroll
    for (int n = 0; n < 4; ++n) {
      int col = n0 + wn + n * 16 + r16;
      float bcol = bias[col];
#pragma unroll
      for (int r = 0; r < 4; ++r) {
        int grow = rbase + r;
        float g = gate4[(size_t)grow * 4];
        float v = acc[m][n][r];
        if (MODE == 1) {
          v += bcol;
          v = fmaxf(v, 0.f);
          v *= g;
          OutB[(size_t)grow * ldc + col] = f2bf(v);
        } else {
          v += g * bcol;
          size_t oi = (size_t)grow * ldc + col;
          if (accumulate) v += FOut[oi];
          FOut[oi] = v;
        }
      }
    }
  }
}

template <int MODE>
__global__ __launch_bounds__(256, 2)
void gemm_kernel(const short* __restrict__ A, const short* __restrict__ Bt, int K, int NTN,
                 const float* __restrict__ bias, const float* __restrict__ gate4,
                 short* __restrict__ OutB, float* __restrict__ FOut, int ldc, int accumulate) {
  __shared__ short sA[128 * 64];
  __shared__ short sB[128 * 64];
  gemm_body<MODE>(sA, sB, A, Bt, K, gridDim.x / NTN, NTN, blockIdx.x,
                  bias, gate4, OutB, FOut, ldc, accumulate);
}

// ===== NEW: 256x256 8-wave 4-phase/K-tile pipeline, de-poisoned (no sched_barrier/lgkm asm) ====
// LDS [2 buf][256][64] per operand (128 KiB). Swizzle jc = chunk ^ (row&7) (R1-proven, 0 confl).
// Per wave 128x64 out, acc[8][4]. Phases per K-tile t (buf c = t&1):
//  P1 (mh0,ks0): reads A0ks0[4]+B ks0[4]; stage A1(t+1) -> buf^1
//  P2 (mh1,ks0): reads A1ks0[4]
//  P3 (mh0,ks1): reads A0ks1[4]+B ks1[4]
//  P4 (mh1,ks1): reads A1ks1[4]; stage A0,B0,B1(t+2) -> buf c; after MFMA: vmcnt(6)
// Publication ledger: vmcnt(6)@P4(t-1) drains all 8 loads of tile t (issued >=3 phases prior,
// ~>1000cyc HBM cover) before any P(t) read; every overwritten slot's last reader was drained
// by its own MFMA dependency + phase-end barrier >=1 phase before the staging issue.
#define FBAR() do { asm volatile("" ::: "memory"); __builtin_amdgcn_s_barrier(); \
                    asm volatile("" ::: "memory"); } while (0)

template <int MODE>
__global__ __launch_bounds__(512, 2)
void gemm256v2(const short* __restrict__ A, const short* __restrict__ Bt, int K, int NTN,
               const float* __restrict__ bias, const float* __restrict__ gate4,
               short* __restrict__ OutB, float* __restrict__ FOut, int ldc, int accumulate) {
  __shared__ short sA[32768];
  __shared__ short sB[32768];
  const int nwg = gridDim.x;
  const int NTM = nwg / NTN;
  int tile_m, tile_n;
  if ((NTM & 7) == 0 && (NTN & 3) == 0) {
    const int m_own = NTM >> 3;
    const int xcd = blockIdx.x & 7;
    const int idx = blockIdx.x >> 3;
    const int mgrp = (m_own < 8) ? m_own : 8;
    const int per = mgrp * 4;
    const int pos = idx % per;
    const int chunk = idx / per;
    const int ml = pos % mgrp;
    const int nl = pos / mgrp;
    const int nchunks = NTN >> 2;
    const int nc = chunk % nchunks;
    const int mg2 = chunk / nchunks;
    tile_m = xcd * m_own + mg2 * mgrp + ml;
    tile_n = nc * 4 + nl;
  } else {
    tile_m = blockIdx.x / NTN;
    tile_n = blockIdx.x % NTN;
  }
  const int m0 = tile_m * 256;
  const int n0 = tile_n * 256;

  const int tid = threadIdx.x;
  const int lane = tid & 63;
  const int wid = tid >> 6;
  const int wm = wid >> 2, wn = wid & 3;   // 2 x 4 wave grid
  const int r16 = lane & 15, kg = lane >> 4;
  // staging geometry: thread -> rows (tid>>3), (tid>>3)+64 of a 128-row half-slot, chunk tid&7
  const int hrow = tid >> 3;
  const int jg8 = ((tid & 7) ^ (hrow & 7)) << 3;  // inverse-swizzled global chunk (shorts)
  const int st0 = tid * 8;                        // linear LDS dst (shorts)
  const short* Asrc = A + (size_t)(m0 + hrow) * K + jg8;
  const short* Bsrc = Bt + (size_t)(n0 + hrow) * K + jg8;
  const size_t rK64 = (size_t)64 * K;
  const size_t rK128 = (size_t)128 * K;

#define STGA0(tt) do { const short* g_ = Asrc + (size_t)(tt) * 64;                        \
    short* d_ = sA + (((tt) & 1) << 14) + st0;                                            \
    GLOAD_LDS16(g_, d_); GLOAD_LDS16(g_ + rK64, d_ + 4096); } while (0)
#define STGA1(tt) do { const short* g_ = Asrc + rK128 + (size_t)(tt) * 64;                \
    short* d_ = sA + (((tt) & 1) << 14) + 8192 + st0;                                     \
    GLOAD_LDS16(g_, d_); GLOAD_LDS16(g_ + rK64, d_ + 4096); } while (0)
#define STGB0(tt) do { const short* g_ = Bsrc + (size_t)(tt) * 64;                        \
    short* d_ = sB + (((tt) & 1) << 14) + st0;                                            \
    GLOAD_LDS16(g_, d_); GLOAD_LDS16(g_ + rK64, d_ + 4096); } while (0)
#define STGB1(tt) do { const short* g_ = Bsrc + rK128 + (size_t)(tt) * 64;                \
    short* d_ = sB + (((tt) & 1) << 14) + 8192 + st0;                                     \
    GLOAD_LDS16(g_, d_); GLOAD_LDS16(g_ + rK64, d_ + 4096); } while (0)
#define RDA(dst, mh, ks)                                                                  \
  _Pragma("unroll") for (int fm = 0; fm < 4; ++fm) {                                      \
    const int ra = wm * 128 + (mh) * 64 + fm * 16 + r16;                                  \
    const int jc = ((ks) * 4 + kg) ^ (ra & 7);                                            \
    dst[fm] = *(const short8*)(sA + cbuf + ra * 64 + jc * 8);                             \
  }
#define RDB(ks)                                                                           \
  _Pragma("unroll") for (int fn = 0; fn < 4; ++fn) {                                      \
    const int rb = wn * 64 + fn * 16 + r16;                                               \
    const int jc = ((ks) * 4 + kg) ^ (rb & 7);                                            \
    bfr[fn] = *(const short8*)(sB + cbuf + rb * 64 + jc * 8);                             \
  }
#define MFMA4(lo, srcA)                                                                   \
  __builtin_amdgcn_s_setprio(1);                                                          \
  _Pragma("unroll") for (int fm = 0; fm < 4; ++fm)                                        \
    _Pragma("unroll") for (int fn = 0; fn < 4; ++fn)                                      \
      acc[(lo) + fm][fn] = __builtin_amdgcn_mfma_f32_16x16x32_bf16(                       \
          srcA[fm], bfr[fn], acc[(lo) + fm][fn], 0, 0, 0);                                \
  __builtin_amdgcn_s_setprio(0);

  float4v acc[8][4];
#pragma unroll
  for (int m = 0; m < 8; ++m)
#pragma unroll
    for (int n = 0; n < 4; ++n) acc[m][n] = (float4v)0.0f;

  short8 aS0[4], aS1[4], bfr[4];
  const int T = K >> 6;

  // prologue: full tile 0 (8 loads) + trio of tile 1 (6 loads); drain tile 0 only.
  STGA0(0); STGA1(0); STGB0(0); STGB1(0);
  if (T > 1) { STGA0(1); STGB0(1); STGB1(1); }
  if (T > 1) asm volatile("s_waitcnt vmcnt(6)" ::: "memory");
  else       asm volatile("s_waitcnt vmcnt(0)" ::: "memory");
  FBAR();

  for (int t = 0; t < T; ++t) {
    const int cbuf = (t & 1) << 14;
    // ---- P1 ----
    RDA(aS0, 0, 0); RDB(0);
    if (t + 1 < T) STGA1(t + 1);
    FBAR();
    MFMA4(0, aS0);
    FBAR();
    // ---- P2 ----
    RDA(aS1, 1, 0);
    FBAR();
    MFMA4(4, aS1);
    FBAR();
    // ---- P3 ----
    RDA(aS0, 0, 1); RDB(1);
    FBAR();
    MFMA4(0, aS0);
    FBAR();
    // ---- P4 ----
    RDA(aS1, 1, 1);
    if (t + 2 < T) { STGA0(t + 2); STGB0(t + 2); STGB1(t + 2); }
    FBAR();
    MFMA4(4, aS1);
    if (t + 2 < T) asm volatile("s_waitcnt vmcnt(6)" ::: "memory");
    else           asm volatile("s_waitcnt vmcnt(0)" ::: "memory");
    FBAR();
  }
#undef STGA0
#undef STGA1
#undef STGB0
#undef STGB1
#undef RDA
#undef RDB
#undef MFMA4

  // epilogue: C/D layout col = lane&15, row = (lane>>4)*4 + reg  [m89/m91]
#pragma unroll
  for (int i = 0; i < 8; ++i) {
    const int rbase = m0 + wm * 128 + (i >> 2) * 64 + (i & 3) * 16 + kg * 4;
#pragma unroll
    for (int fn = 0; fn < 4; ++fn) {
      const int col = n0 + wn * 64 + fn * 16 + r16;
      float bcol = bias[col];
#pragma unroll
      for (int r = 0; r < 4; ++r) {
        int grow = rbase + r;
        float g = gate4[(size_t)grow * 4];
        float v = acc[i][fn][r];
        if (MODE == 1) {
          v += bcol;
          v = fmaxf(v, 0.f);
          v *= g;
          OutB[(size_t)grow * ldc + col] = f2bf(v);
        } else {
          v += g * bcol;
          size_t oi = (size_t)grow * ldc + col;
          if (accumulate) v += FOut[oi];
          FOut[oi] = v;
        }
      }
    }
  }
}

extern "C" void kernel_launch(void* const* d_in, const int* in_sizes, int n_in,
                              void* d_out, int out_size, void* d_ws, size_t ws_size,
                              hipStream_t stream) {
  const float* q  = (const float*)d_in[0];
  const float* k  = (const float*)d_in[1];
  const float* W1 = (const float*)d_in[2];
  const float* b1 = (const float*)d_in[3];
  const float* W2 = (const float*)d_in[4];
  const float* b2 = (const float*)d_in[5];
  const float* Wg = (const float*)d_in[6];
  const float* bg = (const float*)d_in[7];
  float* out = (float*)d_out;

  char* ws = (char*)d_ws;
  size_t off = 0;
  float* gate = (float*)(ws + off); off += (size_t)N_TOK * 4 * sizeof(float);
  short* qb   = (short*)(ws + off); off += (size_t)N_TOK * DIM * 2;
  short* W1t  = (short*)(ws + off); off += (size_t)NEXP * (size_t)DIM * HID * 2;  // [E][H][D]
  short* W2t  = (short*)(ws + off); off += (size_t)NEXP * (size_t)HID * DIM * 2;  // [E][D][H]
  const size_t fixed = off;

  gatecvt_kernel<<<dim3(N_TOK / 4), dim3(256), 0, stream>>>(q, k, Wg, bg, gate, qb);
  transpose_bf16_kernel<<<dim3(HID / 64, DIM / 64, NEXP), dim3(256), 0, stream>>>(W1, W1t, DIM, HID);
  transpose_bf16_kernel<<<dim3(DIM / 64, HID / 64, NEXP), dim3(256), 0, stream>>>(W2, W2t, HID, DIM);

  size_t avail = (ws_size > fixed) ? ws_size - fixed : 0;

  if ((size_t)N_TOK * HID * 2 <= avail) {
    // full-M per-expert; A/B: expert-0 G1 on the new 256^2 pipeline, rest on proven 128^2.
    short* Hs = (short*)(ws + fixed);
    for (int e = 0; e < NEXP; ++e) {
      if (e == 0) {
        gemm256v2<1><<<dim3((N_TOK / 256) * (HID / 256)), dim3(512), 0, stream>>>(
            qb, W1t, DIM, HID / 256, b1, gate, Hs, nullptr, HID, 0);
      } else {
        gemm_kernel<1><<<dim3((N_TOK / 128) * (HID / 128)), dim3(256), 0, stream>>>(
            qb, W1t + (size_t)e * HID * DIM, DIM, HID / 128,
            b1 + (size_t)e * HID, gate + e, Hs, nullptr, HID, 0);
      }
      gemm_kernel<2><<<dim3((N_TOK / 128) * (DIM / 128)), dim3(256), 0, stream>>>(
          Hs, W2t + (size_t)e * DIM * HID, HID, DIM / 128,
          b2 + (size_t)e * DIM, gate + e, nullptr, out, DIM, e > 0);
    }
  } else {
    // row-chunked per-expert fallback (tiny ws)
    short* Hs = (short*)(ws + fixed);
    long long mc = (long long)(avail / ((size_t)HID * 2));
    mc &= ~127LL;
    if (mc < 128) mc = 128;
    if (mc > N_TOK) mc = N_TOK;
    for (int cb = 0; cb < N_TOK; cb += (int)mc) {
      int rows = (N_TOK - cb < (int)mc) ? (N_TOK - cb) : (int)mc;
      for (int e = 0; e < NEXP; ++e) {
        gemm_kernel<1><<<dim3((rows / 128) * (HID / 128)), dim3(256), 0, stream>>>(
            qb + (size_t)cb * DIM, W1t + (size_t)e * HID * DIM, DIM, HID / 128,
            b1 + (size_t)e * HID, gate + (size_t)cb * 4 + e, Hs, nullptr, HID, 0);
        gemm_kernel<2><<<dim3((rows / 128) * (DIM / 128)), dim3(256), 0, stream>>>(
            Hs, W2t + (size_t)e * DIM * HID, HID, DIM / 128,
            b2 + (size_t)e * DIM, gate + (size_t)cb * 4 + e, nullptr,
            out + (size_t)cb * DIM, DIM, e > 0);
      }
    }
  }
}

// Round 10
// 1265.069 us; speedup vs baseline: 1.0291x; 1.0291x over previous
//
#include <hip/hip_runtime.h>
#include <hip/hip_bf16.h>

#define N_TOK 16384
#define DIM   1024
#define NEXP  4
#define HID   4096
#define CHK   8192   // token half-chunk for the G1/G2 software pipeline

typedef __attribute__((ext_vector_type(8))) short short8;
typedef __attribute__((ext_vector_type(4))) short short4v;
typedef __attribute__((ext_vector_type(4))) float float4v;

static __device__ __forceinline__ short f2bf(float f) {
  __hip_bfloat16 h = __float2bfloat16(f);
  return *reinterpret_cast<short*>(&h);
}

#define GLOAD_LDS16(gsrc, ldst)                                                            \
  __builtin_amdgcn_global_load_lds((const __attribute__((address_space(1))) void*)(gsrc),  \
                                   (__attribute__((address_space(3))) void*)(ldst), 16, 0, 0)

// ---------------- shared bodies ----------------

// LDS-tiled transpose+convert: src[z][R][C] f32 -> dst[z][C][R] bf16
__device__ __forceinline__ void transpose_body(const float* __restrict__ src0,
                                               short* __restrict__ dst0, int R, int C,
                                               int bx, int by, int bz, float (*tile)[65]) {
  const size_t eoff = (size_t)bz * (size_t)R * C;
  const float* src = src0 + eoff;
  short* dst = dst0 + eoff;
  const int r0 = by * 64, c0 = bx * 64;
  const int tc = threadIdx.x & 63, tr = threadIdx.x >> 6;
#pragma unroll
  for (int p = 0; p < 16; ++p) {
    int r = p * 4 + tr;
    tile[r][tc] = src[(size_t)(r0 + r) * C + (c0 + tc)];
  }
  __syncthreads();
#pragma unroll
  for (int p = 0; p < 16; ++p) {
    int i = p * 4 + tr;
    dst[(size_t)(c0 + i) * R + (r0 + tc)] = f2bf(tile[tc][i]);
  }
}

// fused gate (softmax(concat(q,k)@Wg+bg)) + q->bf16 convert; one wave per token
__device__ __forceinline__ void gatecvt_body(const float* __restrict__ q,
                                             const float* __restrict__ k,
                                             const float* __restrict__ Wg,
                                             const float* __restrict__ bg,
                                             float* __restrict__ gate, short* __restrict__ qb,
                                             int bid) {
  const int wave = threadIdx.x >> 6, lane = threadIdx.x & 63;
  const int n = bid * 4 + wave;
  const float* qr = q + (size_t)n * DIM;
  const float* kr = k + (size_t)n * DIM;
  short* qbr = qb + (size_t)n * DIM;
  float s0 = 0.f, s1 = 0.f, s2 = 0.f, s3 = 0.f;
#pragma unroll
  for (int it = 0; it < 4; ++it) {
    int d = it * 256 + lane * 4;
    float4 qv = *(const float4*)(qr + d);
    float4 kv = *(const float4*)(kr + d);
    short4v o;
    o[0] = f2bf(qv.x); o[1] = f2bf(qv.y); o[2] = f2bf(qv.z); o[3] = f2bf(qv.w);
    *(short4v*)(qbr + d) = o;
    const float xq[4] = {qv.x, qv.y, qv.z, qv.w};
    const float xk[4] = {kv.x, kv.y, kv.z, kv.w};
#pragma unroll
    for (int j = 0; j < 4; ++j) {
      float4 w = *(const float4*)(Wg + (size_t)(d + j) * 4);
      s0 += xq[j] * w.x; s1 += xq[j] * w.y; s2 += xq[j] * w.z; s3 += xq[j] * w.w;
      float4 w2 = *(const float4*)(Wg + (size_t)(DIM + d + j) * 4);
      s0 += xk[j] * w2.x; s1 += xk[j] * w2.y; s2 += xk[j] * w2.z; s3 += xk[j] * w2.w;
    }
  }
  for (int off = 32; off; off >>= 1) {
    s0 += __shfl_xor(s0, off);
    s1 += __shfl_xor(s1, off);
    s2 += __shfl_xor(s2, off);
    s3 += __shfl_xor(s3, off);
  }
  if (lane == 0) {
    float l0 = s0 + bg[0], l1 = s1 + bg[1], l2 = s2 + bg[2], l3 = s3 + bg[3];
    float m = fmaxf(fmaxf(l0, l1), fmaxf(l2, l3));
    float e0 = expf(l0 - m), e1 = expf(l1 - m), e2 = expf(l2 - m), e3 = expf(l3 - m);
    float inv = 1.f / (e0 + e1 + e2 + e3);
    float4 g; g.x = e0 * inv; g.y = e1 * inv; g.z = e2 * inv; g.w = e3 * inv;
    *(float4*)(gate + (size_t)n * 4) = g;
  }
}

// ---------------- merged prep dispatch: gatecvt (4096) + W1t (4096) [+ W2t (4096)] ----------
__global__ __launch_bounds__(256)
void prep_kernel(const float* __restrict__ q, const float* __restrict__ k,
                 const float* __restrict__ Wg, const float* __restrict__ bg,
                 float* __restrict__ gate, short* __restrict__ qb,
                 const float* __restrict__ W1, short* __restrict__ W1t,
                 const float* __restrict__ W2, short* __restrict__ W2t) {
  __shared__ float tile[64][65];
  const int bid = blockIdx.x;
  if (bid < N_TOK / 4) {
    gatecvt_body(q, k, Wg, bg, gate, qb, bid);
  } else if (bid < N_TOK / 4 + (HID / 64) * (DIM / 64) * NEXP) {
    int i = bid - N_TOK / 4;                        // W1 [E][D][H] -> W1t [E][H][D]
    transpose_body(W1, W1t, DIM, HID, i % (HID / 64), (i / (HID / 64)) % (DIM / 64),
                   i / ((HID / 64) * (DIM / 64)), tile);
  } else {
    int i = bid - N_TOK / 4 - (HID / 64) * (DIM / 64) * NEXP;  // W2 [E][H][D] -> W2t [E][D][H]
    transpose_body(W2, W2t, HID, DIM, i % (DIM / 64), (i / (DIM / 64)) % (HID / 64),
                   i / ((DIM / 64) * (HID / 64)), tile);
  }
}

// ===== R7/R8-proven 128x128 GEMM body (880 TF class): 2-barrier, gload_lds, XOR swizzle,
// XCD-locality tile order. MODE 1: Hs = bf16(gate*relu(C+b1)); MODE 2: out (+)= C + gate*b2.
template <int MODE>
__device__ __forceinline__ void gemm_body(short* sA, short* sB,
                                          const short* __restrict__ A, const short* __restrict__ Bt,
                                          int K, int NTM, int NTN, int bid,
                                          const float* __restrict__ bias,
                                          const float* __restrict__ gate4,
                                          short* __restrict__ OutB, float* __restrict__ FOut,
                                          int ldc, int accumulate) {
  int tile_m, tile_n;
  {
    const int m_own = NTM >> 3;
    const int xcd = bid & 7;
    const int idx = bid >> 3;
    const int mgrp = (m_own < 8) ? m_own : 8;
    const int per = mgrp * 4;
    const int pos = idx % per;
    const int chunk = idx / per;
    const int ml = pos % mgrp;
    const int nl = pos / mgrp;
    const int nchunks = NTN >> 2;
    const int nc = chunk % nchunks;
    const int mg2 = chunk / nchunks;
    tile_m = xcd * m_own + mg2 * mgrp + ml;
    tile_n = nc * 4 + nl;
  }
  const int m0 = tile_m * 128;
  const int n0 = tile_n * 128;

  const int t = threadIdx.x;
  const int lane = t & 63;
  const int wave = t >> 6;
  const int wm = (wave >> 1) * 64;
  const int wn = (wave & 1) * 64;
  const int r16 = lane & 15;
  const int kg = lane >> 4;

  float4v acc[4][4];
#pragma unroll
  for (int m = 0; m < 4; ++m)
#pragma unroll
    for (int n = 0; n < 4; ++n) acc[m][n] = (float4v)0.0f;

  for (int k0 = 0; k0 < K; k0 += 64) {
#pragma unroll
    for (int i = 0; i < 4; ++i) {
      int c = i * 256 + t;
      int row = c >> 3;
      int jc = (c & 7) ^ (row & 7);
      GLOAD_LDS16(A + (size_t)(m0 + row) * K + k0 + jc * 8, &sA[c * 8]);
      GLOAD_LDS16(Bt + (size_t)(n0 + row) * K + k0 + jc * 8, &sB[c * 8]);
    }
    __syncthreads();
#pragma unroll
    for (int kk = 0; kk < 2; ++kk) {
      short8 af[4], bfr[4];
#pragma unroll
      for (int m = 0; m < 4; ++m) {
        int row = wm + m * 16 + r16;
        int jc = (kk * 4 + kg) ^ (row & 7);
        af[m] = *(const short8*)&sA[row * 64 + jc * 8];
      }
#pragma unroll
      for (int n = 0; n < 4; ++n) {
        int row = wn + n * 16 + r16;
        int jc = (kk * 4 + kg) ^ (row & 7);
        bfr[n] = *(const short8*)&sB[row * 64 + jc * 8];
      }
#pragma unroll
      for (int m = 0; m < 4; ++m)
#pragma unroll
        for (int n = 0; n < 4; ++n)
          acc[m][n] = __builtin_amdgcn_mfma_f32_16x16x32_bf16(af[m], bfr[n], acc[m][n], 0, 0, 0);
    }
    __syncthreads();
  }

  // epilogue: C/D layout col = lane&15, row = (lane>>4)*4 + reg  [m89/m91]
#pragma unroll
  for (int m = 0; m < 4; ++m) {
    int rbase = m0 + wm + m * 16 + kg * 4;
#pragma unroll
    for (int n = 0; n < 4; ++n) {
      int col = n0 + wn + n * 16 + r16;
      float bcol = bias[col];
#pragma unroll
      for (int r = 0; r < 4; ++r) {
        int grow = rbase + r;
        float g = gate4[(size_t)grow * 4];
        float v = acc[m][n][r];
        if (MODE == 1) {
          v += bcol;
          v = fmaxf(v, 0.f);
          v *= g;
          OutB[(size_t)grow * ldc + col] = f2bf(v);
        } else {
          v += g * bcol;
          size_t oi = (size_t)grow * ldc + col;
          if (accumulate) v += FOut[oi];
          FOut[oi] = v;
        }
      }
    }
  }
}

// ------- co-scheduled dispatch with three roles:
//   [0, g2n)            : GEMM2 chunk (long K=4096 blocks, dispatched first)
//   [g2n, g2n+g1n)      : GEMM1 chunk (short K=1024 blocks, backfill)
//   [g2n+g1n, ...)      : W2-transpose blocks (d0 only; shortest, fill ragged tail)
__global__ __launch_bounds__(256, 2)
void fused_kernel(const short* __restrict__ g1A, const short* __restrict__ g1B,
                  const float* __restrict__ g1bias, const float* __restrict__ g1gate,
                  short* __restrict__ g1out,
                  const short* __restrict__ g2A, const short* __restrict__ g2B,
                  const float* __restrict__ g2bias, const float* __restrict__ g2gate,
                  float* __restrict__ g2out, int g2accum, int g2n, int g1n,
                  const float* __restrict__ tsrc, short* __restrict__ tdst) {
  __shared__ short smem[2 * 128 * 64];
  const int bid = blockIdx.x;
  if (bid < g2n) {
    gemm_body<2>(smem, smem + 8192, g2A, g2B, HID, CHK / 128, DIM / 128, bid,
                 g2bias, g2gate, nullptr, g2out, DIM, g2accum);
  } else if (bid < g2n + g1n) {
    gemm_body<1>(smem, smem + 8192, g1A, g1B, DIM, CHK / 128, HID / 128, bid - g2n,
                 g1bias, g1gate, g1out, nullptr, HID, 0);
  } else {
    int i = bid - g2n - g1n;  // W2 [E][H][D] -> W2t [E][D][H]
    transpose_body(tsrc, tdst, HID, DIM, i % (DIM / 64), (i / (DIM / 64)) % (HID / 64),
                   i / ((DIM / 64) * (HID / 64)), (float(*)[65])smem);
  }
}

// ---------------- standalone GEMM (fallback path), grid = NTM*NTN ----------------
template <int MODE>
__global__ __launch_bounds__(256, 2)
void gemm_kernel(const short* __restrict__ A, const short* __restrict__ Bt, int K, int NTN,
                 const float* __restrict__ bias, const float* __restrict__ gate4,
                 short* __restrict__ OutB, float* __restrict__ FOut, int ldc, int accumulate) {
  __shared__ short smem[2 * 128 * 64];
  gemm_body<MODE>(smem, smem + 8192, A, Bt, K, gridDim.x / NTN, NTN, blockIdx.x,
                  bias, gate4, OutB, FOut, ldc, accumulate);
}

extern "C" void kernel_launch(void* const* d_in, const int* in_sizes, int n_in,
                              void* d_out, int out_size, void* d_ws, size_t ws_size,
                              hipStream_t stream) {
  const float* q  = (const float*)d_in[0];
  const float* k  = (const float*)d_in[1];
  const float* W1 = (const float*)d_in[2];
  const float* b1 = (const float*)d_in[3];
  const float* W2 = (const float*)d_in[4];
  const float* b2 = (const float*)d_in[5];
  const float* Wg = (const float*)d_in[6];
  const float* bg = (const float*)d_in[7];
  float* out = (float*)d_out;

  char* ws = (char*)d_ws;
  size_t off = 0;
  float* gate = (float*)(ws + off); off += (size_t)N_TOK * 4 * sizeof(float);
  short* qb   = (short*)(ws + off); off += (size_t)N_TOK * DIM * 2;
  short* W1t  = (short*)(ws + off); off += (size_t)NEXP * (size_t)DIM * HID * 2;  // [E][H][D]
  short* W2t  = (short*)(ws + off); off += (size_t)NEXP * (size_t)HID * DIM * 2;  // [E][D][H]
  const size_t fixed = off;

  const int GATEB = N_TOK / 4;                          // 4096
  const int W1TB  = (HID / 64) * (DIM / 64) * NEXP;     // 4096
  const int W2TB  = (DIM / 64) * (HID / 64) * NEXP;     // 4096

  size_t avail = (ws_size > fixed) ? ws_size - fixed : 0;
  const size_t hs_half = (size_t)CHK * HID * 2;  // 64 MB

  if (2 * hs_half <= avail) {
    // prep: gatecvt + W1-transpose only (W2-transpose folded into d0)
    prep_kernel<<<dim3(GATEB + W1TB), dim3(256), 0, stream>>>(
        q, k, Wg, bg, gate, qb, W1, W1t, W2, W2t);

    short* HsA = (short*)(ws + fixed);
    short* HsB = (short*)(ws + fixed + hs_half);
    short* hs[2] = {HsA, HsB};
    const int G1BLK = (CHK / 128) * (HID / 128);  // 2048
    const int G2BLK = (CHK / 128) * (DIM / 128);  // 512

    // d0: G1(c0, e0) -> HsA, co-scheduled with the W2 transpose (needed from d1 on)
    fused_kernel<<<dim3(G1BLK + W2TB), dim3(256), 0, stream>>>(
        qb, W1t, b1, gate, HsA,
        nullptr, nullptr, nullptr, nullptr, nullptr, 0, 0, G1BLK, W2, W2t);
    // d1..d7: step s covers G1(c=(s+1)&1, e=(s+1)>>1) and G2(c=s&1, e=s>>1)
    for (int s = 0; s < 7; ++s) {
      const int c1 = (s + 1) & 1, e1 = (s + 1) >> 1;   // G1 target
      const int c2 = s & 1,       e2 = s >> 1;         // G2 source
      fused_kernel<<<dim3(G2BLK + G1BLK), dim3(256), 0, stream>>>(
          qb + (size_t)c1 * CHK * DIM, W1t + (size_t)e1 * HID * DIM,
          b1 + (size_t)e1 * HID, gate + (size_t)c1 * CHK * 4 + e1, hs[c1],
          hs[c2], W2t + (size_t)e2 * DIM * HID,
          b2 + (size_t)e2 * DIM, gate + (size_t)c2 * CHK * 4 + e2,
          out + (size_t)c2 * CHK * DIM, (e2 > 0) ? 1 : 0, G2BLK, G1BLK,
          nullptr, nullptr);
    }
    // d8: G2(c1, e3) from HsB
    fused_kernel<<<dim3(G2BLK), dim3(256), 0, stream>>>(
        nullptr, nullptr, nullptr, nullptr, nullptr,
        hs[1], W2t + (size_t)3 * DIM * HID, b2 + (size_t)3 * DIM,
        gate + (size_t)CHK * 4 + 3, out + (size_t)CHK * DIM, 1, G2BLK, 0,
        nullptr, nullptr);
  } else {
    // row-chunked per-expert fallback (tiny ws): full prep in one dispatch
    prep_kernel<<<dim3(GATEB + W1TB + W2TB), dim3(256), 0, stream>>>(
        q, k, Wg, bg, gate, qb, W1, W1t, W2, W2t);
    short* Hs = (short*)(ws + fixed);
    long long mc = (long long)(avail / ((size_t)HID * 2));
    mc &= ~127LL;
    if (mc < 128) mc = 128;
    if (mc > N_TOK) mc = N_TOK;
    for (int cb = 0; cb < N_TOK; cb += (int)mc) {
      int rows = (N_TOK - cb < (int)mc) ? (N_TOK - cb) : (int)mc;
      for (int e = 0; e < NEXP; ++e) {
        gemm_kernel<1><<<dim3((rows / 128) * (HID / 128)), dim3(256), 0, stream>>>(
            qb + (size_t)cb * DIM, W1t + (size_t)e * HID * DIM, DIM, HID / 128,
            b1 + (size_t)e * HID, gate + (size_t)cb * 4 + e, Hs, nullptr, HID, 0);
        gemm_kernel<2><<<dim3((rows / 128) * (DIM / 128)), dim3(256), 0, stream>>>(
            Hs, W2t + (size_t)e * DIM * HID, HID, DIM / 128,
            b2 + (size_t)e * DIM, gate + (size_t)cb * 4 + e, nullptr,
            out + (size_t)cb * DIM, DIM, e > 0);
      }
    }
  }
}